// Round 6
// baseline (75.876 us; speedup 1.0000x reference)
//
#include <hip/hip_runtime.h>
#include <hip/hip_bf16.h>

// B=128, C=32, K=128
// out[b,c,i,j] = s[b,c],  s[b,c] = sum_k (u[k]+b_row[c]) * (v[k]+b_col[c])
//   u[k] = sum_i w_row[c,i] * X[b,i,k]   (coalesced column-dot: lane = k)
//   v[k] = sum_j w_col[c,j] * X[b,k,j]   (per-lane row walk, float4)
//
// FUSED single kernel: one block per (b,c). Each block redundantly computes
// s[b,c] (~128 L2-hit VMEM reads + ~128 FMA per thread) then streams its
// 64 KB broadcast write. Compute hides under the 268 MB write stream
// (pure-write floor ~39 us at the fill kernel's ~6.9 TB/s).
//
// XCD-locality: dispatcher maps block i -> XCD i%8. We assign
//   xcd = blockIdx&7,  b = xcd*16 + (idx&15),  c = idx>>4
// so each XCD's L2 only ever reads its own 16 X_b slabs (1 MB) -> HBM read
// stays ~8.4 MB instead of 8x re-fetch. Bijective since 4096 % 8 == 0.

constexpr int KDIM = 128;
constexpr int CDIM = 32;

__global__ __launch_bounds__(256) void fused_kernel(
    const float* __restrict__ x,
    const float* __restrict__ w_col, const float* __restrict__ b_col,
    const float* __restrict__ w_row, const float* __restrict__ b_row,
    float* __restrict__ out)
{
    const int xcd = blockIdx.x & 7;
    const int idx = blockIdx.x >> 3;          // 0..511
    const int b   = xcd * 16 + (idx & 15);    // XCD-partitioned batch
    const int c   = idx >> 4;                 // 0..31

    __shared__ float wr_s[KDIM];
    __shared__ float wc_s[KDIM];
    __shared__ float uvp[4][KDIM];            // u half0/half1, v half0/half1
    __shared__ float psum[2];

    const int tid = threadIdx.x;
    const int k   = tid & 127;
    const int h   = tid >> 7;                 // wave-uniform (waves 0,1 -> 0; 2,3 -> 1)

    if (tid < 128)      wr_s[tid]       = w_row[c * KDIM + tid];
    else                wc_s[tid - 128] = w_col[c * KDIM + (tid - 128)];
    __syncthreads();

    const float* Xb = x + (size_t)b * KDIM * KDIM;

    // ---- u[k] partial over i in [64h, 64h+64): coalesced 256B/wave reads ----
    float ua = 0.f;
    #pragma unroll 8
    for (int i = 0; i < 64; ++i) {
        ua = fmaf(wr_s[64 * h + i], Xb[(64 * h + i) * KDIM + k], ua);
    }
    // ---- v[k] partial over j in [64h, 64h+64): per-lane row walk, float4 ----
    float va = 0.f;
    const float4* xr = reinterpret_cast<const float4*>(Xb + k * KDIM + 64 * h);
    #pragma unroll 4
    for (int jq = 0; jq < 16; ++jq) {
        const float4 xv = xr[jq];
        const int j0 = 64 * h + 4 * jq;
        va = fmaf(wc_s[j0 + 0], xv.x, va);
        va = fmaf(wc_s[j0 + 1], xv.y, va);
        va = fmaf(wc_s[j0 + 2], xv.z, va);
        va = fmaf(wc_s[j0 + 3], xv.w, va);
    }
    uvp[h][k]     = ua;
    uvp[2 + h][k] = va;
    __syncthreads();

    // ---- combine halves, product, reduce 128 -> 1 ----
    if (tid < 128) {
        const float br = b_row[c];   // c block-uniform -> s_load
        const float bc = b_col[c];
        float p = (uvp[0][tid] + uvp[1][tid] + br) *
                  (uvp[2][tid] + uvp[3][tid] + bc);
        #pragma unroll
        for (int off = 32; off; off >>= 1) p += __shfl_xor(p, off, 64);
        if ((tid & 63) == 0) psum[tid >> 6] = p;
    }
    __syncthreads();
    const float s = psum[0] + psum[1];

    // ---- stream the 64 KB slab (plain stores; nt regressed in R3) ----
    float4 v4;
    v4.x = v4.y = v4.z = v4.w = s;
    float4* o = reinterpret_cast<float4*>(out) + (size_t)(b * CDIM + c) * 4096;
    #pragma unroll
    for (int r = 0; r < 16; ++r) {
        o[tid + 256 * r] = v4;
    }
}

extern "C" void kernel_launch(void* const* d_in, const int* in_sizes, int n_in,
                              void* d_out, int out_size, void* d_ws, size_t ws_size,
                              hipStream_t stream) {
    const float* x     = (const float*)d_in[0];
    const float* w_col = (const float*)d_in[1];
    const float* b_col = (const float*)d_in[2];
    const float* w_row = (const float*)d_in[3];
    const float* b_row = (const float*)d_in[4];
    float* out = (float*)d_out;

    fused_kernel<<<4096, 256, 0, stream>>>(x, w_col, b_col, w_row, b_row, out);
}

// Round 7
// 58.584 us; speedup vs baseline: 1.2952x; 1.2952x over previous
//
#include <hip/hip_runtime.h>
#include <hip/hip_bf16.h>

// B=128, C=32, K=128
// out[b,c,i,j] = s[b,c],  s[b,c] = sum_k (u[c,k]+b_row[c]) * (v[c,k]+b_col[c])
//   u[c,k] = sum_i w_row[c,i] * X[b,i,k]
//   v[c,k] = sum_j w_col[c,j] * X[b,k,j]
//
// compute_s v4 (split-k):
//  - grid 512 = (b, ch, kh); bid layout puts all 4 blocks of a b on one XCD
//  - 64 KB LDS/block -> 2 blocks/CU (2 waves/SIMD latency hiding)
//  - wave-uniform c-quad -> weights via s_load (SMEM pipe), zero LDS cost
//  - inner iter: 1 ds_read_b32 (2-way, free) + 4 FMA
// Two-kernel split retained: R6 fusion regressed (write stream at 86% peak
// has no spare VMEM/L2 capacity for interleaved compute reads).

constexpr int KDIM = 128;
constexpr int CDIM = 32;

// grid 512: b = bid&127, ch = (bid>>7)&1, kh = bid>>8
__global__ __launch_bounds__(256, 2) void compute_s_kernel(
    const float* __restrict__ x,
    const float* __restrict__ w_col, const float* __restrict__ b_col,
    const float* __restrict__ w_row, const float* __restrict__ b_row,
    float* __restrict__ s_part)
{
    __shared__ float xs[KDIM][64];   // xs[i][kk] = X[i][64kh+kk]   (32 KB)
    __shared__ float xt[KDIM][64];   // xt[j][kk] = X[64kh+kk][j]   (32 KB)

    const int bid = blockIdx.x;
    const int b   = bid & 127;
    const int ch  = (bid >> 7) & 1;
    const int kh  = bid >> 8;
    const int tid = threadIdx.x;

    const float4* xsrc4 = reinterpret_cast<const float4*>(x + (size_t)b * KDIM * KDIM);

    // ---- stage xs: all 128 rows, k-columns [64kh, +64), coalesced-ish ----
    #pragma unroll
    for (int e = 0; e < 8; ++e) {
        const int idx = tid + 256 * e;        // 0..2047
        const int row = idx >> 4;             // 0..127
        const int q   = idx & 15;             // 0..15
        *reinterpret_cast<float4*>(&xs[row][4 * q]) = xsrc4[row * 32 + kh * 16 + q];
    }
    // ---- stage xt via 4x4 register transpose of X[64kh..+64][0..128) ----
    {
        const int tj = tid & 31;              // j-quad
        const int tk = tid >> 5;              // 0..7
        #pragma unroll
        for (int it = 0; it < 2; ++it) {
            const int kq = tk + 8 * it;       // kk-quad 0..15
            const float4 r0 = xsrc4[(64 * kh + 4 * kq + 0) * 32 + tj];
            const float4 r1 = xsrc4[(64 * kh + 4 * kq + 1) * 32 + tj];
            const float4 r2 = xsrc4[(64 * kh + 4 * kq + 2) * 32 + tj];
            const float4 r3 = xsrc4[(64 * kh + 4 * kq + 3) * 32 + tj];
            *reinterpret_cast<float4*>(&xt[4 * tj + 0][4 * kq]) = make_float4(r0.x, r1.x, r2.x, r3.x);
            *reinterpret_cast<float4*>(&xt[4 * tj + 1][4 * kq]) = make_float4(r0.y, r1.y, r2.y, r3.y);
            *reinterpret_cast<float4*>(&xt[4 * tj + 2][4 * kq]) = make_float4(r0.z, r1.z, r2.z, r3.z);
            *reinterpret_cast<float4*>(&xt[4 * tj + 3][4 * kq]) = make_float4(r0.w, r1.w, r2.w, r3.w);
        }
    }
    __syncthreads();

    const int lane = tid & 63;                              // k offset in half
    const int wv   = __builtin_amdgcn_readfirstlane(tid >> 6);  // wave id 0..3 (SGPR)
    const int c0   = ch * 16 + wv * 4;                      // wave-uniform c-quad base

    const float* wr = w_row + c0 * KDIM;   // uniform base -> s_load stream
    const float* wc = w_col + c0 * KDIM;

    float u0 = 0, u1 = 0, u2 = 0, u3 = 0;
    #pragma unroll 4
    for (int i = 0; i < KDIM; ++i) {
        const float xv = xs[i][lane];
        u0 = fmaf(wr[0 * KDIM + i], xv, u0);
        u1 = fmaf(wr[1 * KDIM + i], xv, u1);
        u2 = fmaf(wr[2 * KDIM + i], xv, u2);
        u3 = fmaf(wr[3 * KDIM + i], xv, u3);
    }
    float v0 = 0, v1 = 0, v2 = 0, v3 = 0;
    #pragma unroll 4
    for (int j = 0; j < KDIM; ++j) {
        const float xv = xt[j][lane];
        v0 = fmaf(wc[0 * KDIM + j], xv, v0);
        v1 = fmaf(wc[1 * KDIM + j], xv, v1);
        v2 = fmaf(wc[2 * KDIM + j], xv, v2);
        v3 = fmaf(wc[3 * KDIM + j], xv, v3);
    }

    const float br0 = b_row[c0 + 0], bc0 = b_col[c0 + 0];
    const float br1 = b_row[c0 + 1], bc1 = b_col[c0 + 1];
    const float br2 = b_row[c0 + 2], bc2 = b_col[c0 + 2];
    const float br3 = b_row[c0 + 3], bc3 = b_col[c0 + 3];

    float p0 = (u0 + br0) * (v0 + bc0);
    float p1 = (u1 + br1) * (v1 + bc1);
    float p2 = (u2 + br2) * (v2 + bc2);
    float p3 = (u3 + br3) * (v3 + bc3);

    #pragma unroll
    for (int off = 32; off; off >>= 1) {
        p0 += __shfl_xor(p0, off);
        p1 += __shfl_xor(p1, off);
        p2 += __shfl_xor(p2, off);
        p3 += __shfl_xor(p3, off);
    }
    if (lane == 0) {
        float* dst = s_part + kh * (128 * CDIM) + b * CDIM + c0;
        dst[0] = p0; dst[1] = p1; dst[2] = p2; dst[3] = p3;
    }
}

// grid = 4096 (one block per (b,c) slab of 16384 floats), block = 256
// Plain float4 stores (nt regressed, R3). Adds the two k-half partials.
__global__ __launch_bounds__(256) void bcast_kernel(
    const float* __restrict__ s_part, float* __restrict__ out)
{
    const int bc = blockIdx.x;
    const float val = s_part[bc] + s_part[128 * CDIM + bc];
    float4 v4;
    v4.x = v4.y = v4.z = v4.w = val;
    float4* o = reinterpret_cast<float4*>(out) + (size_t)bc * 4096;
    #pragma unroll
    for (int r = 0; r < 16; ++r) {
        o[threadIdx.x + 256 * r] = v4;
    }
}

extern "C" void kernel_launch(void* const* d_in, const int* in_sizes, int n_in,
                              void* d_out, int out_size, void* d_ws, size_t ws_size,
                              hipStream_t stream) {
    const float* x     = (const float*)d_in[0];
    const float* w_col = (const float*)d_in[1];
    const float* b_col = (const float*)d_in[2];
    const float* w_row = (const float*)d_in[3];
    const float* b_row = (const float*)d_in[4];
    float* out    = (float*)d_out;
    float* s_part = (float*)d_ws;   // 8192 floats of scratch (both k-half partials)

    compute_s_kernel<<<512, 256, 0, stream>>>(x, w_col, b_col, w_row, b_row, s_part);
    bcast_kernel<<<4096, 256, 0, stream>>>(s_part, out);
}

// Round 8
// 54.681 us; speedup vs baseline: 1.3876x; 1.0714x over previous
//
#include <hip/hip_runtime.h>
#include <hip/hip_bf16.h>

// B=128, C=32, K=128
// out[b,c,i,j] = s[b,c],  s[b,c] = sum_k (u[c,k]+b_row[c]) * (v[c,k]+b_col[c])
//   u[c,k] = sum_i w_row[c,i] * X[b,i,k]
//   v[c,k] = sum_j w_col[c,j] * X[b,k,j] = sum_j w_col[c,j] * XT[j,k]
//
// compute_s v5 (R5 structure + 3 cuts):
//  - merged staging: ONE set of 16 float4 global loads feeds BOTH xs and xt
//    (R5/R7 read X twice; this halves staging traffic + latency exposure)
//  - fused u+v loop: 2 b128 + 2 b64 + 16 FMA per iter (2x MLP per wave;
//    R7 showed occupancy isn't the lever -> in-flight ds_reads per wave is)
//  - weights staged first (their load latency hides under the X transpose)
//  - NO scalar-load weights (R7: SMEM+DS share lgkmcnt, forces drains)
// bcast: 2048 blocks x 2 slabs; plain stores (nt regressed, R3); no fusion
// with compute (R6: write stream at 86% peak can't absorb compute reads).

constexpr int KDIM = 128;
constexpr int CDIM = 32;
constexpr int XS_LD = 132;   // padded row stride for xs (16B-aligned)

// XOR chunk swizzle for the XT tile (linear [128][128]): conflict-free for
// 4x4-transpose b128 staging writes AND row-wise b128 reads (verified R4/R5).
__device__ __forceinline__ int swz_word(int row, int col) {
    return (row << 7) | ((((col >> 2) ^ ((row >> 2) & 7)) << 2) | (col & 3));
}

// grid = 256: blockIdx.x = b*2 + ch ; block = 256 threads
__global__ __launch_bounds__(256) void compute_s_kernel(
    const float* __restrict__ x,
    const float* __restrict__ w_col, const float* __restrict__ b_col,
    const float* __restrict__ w_row, const float* __restrict__ b_row,
    float* __restrict__ s_out)
{
    __shared__ float  xs[KDIM * XS_LD];   // X row-major, padded   (66 KB)
    __shared__ float  xt[KDIM * KDIM];    // X^T, chunk-swizzled   (64 KB)
    __shared__ float2 wpr[KDIM][8];       // (w_row[C0+cg][i], w_row[C0+cg+8][i])  (8 KB)
    __shared__ float2 wpc[KDIM][8];       // same for w_col                         (8 KB)

    const int b   = blockIdx.x >> 1;
    const int ch  = blockIdx.x & 1;
    const int tid = threadIdx.x;
    const int C0  = ch * 16;

    // ---- stage packed weight pairs FIRST (latency hides under transpose) ----
    #pragma unroll
    for (int e = 0; e < 4; ++e) {
        const int idx = tid + 256 * e;           // 0..1023
        const int i   = idx & 127;
        const int cg  = idx >> 7;                // 0..7
        wpr[i][cg] = make_float2(w_row[(C0 + cg) * KDIM + i],
                                 w_row[(C0 + cg + 8) * KDIM + i]);
        wpc[i][cg] = make_float2(w_col[(C0 + cg) * KDIM + i],
                                 w_col[(C0 + cg + 8) * KDIM + i]);
    }

    // ---- merged X staging: 16 float4 loads feed BOTH xs and xt ----
    const float4* xsrc = reinterpret_cast<const float4*>(x + (size_t)b * KDIM * KDIM);
    const int tj  = tid & 31;    // column quad of X
    const int ti0 = tid >> 5;    // 0..7
    #pragma unroll
    for (int it = 0; it < 4; ++it) {
        const int ti = ti0 + 8 * it;                      // row quad of X, 0..31
        const float4 r0 = xsrc[(4 * ti + 0) * 32 + tj];   // coalesced
        const float4 r1 = xsrc[(4 * ti + 1) * 32 + tj];
        const float4 r2 = xsrc[(4 * ti + 2) * 32 + tj];
        const float4 r3 = xsrc[(4 * ti + 3) * 32 + tj];
        // row-major into xs
        *reinterpret_cast<float4*>(&xs[(4 * ti + 0) * XS_LD + 4 * tj]) = r0;
        *reinterpret_cast<float4*>(&xs[(4 * ti + 1) * XS_LD + 4 * tj]) = r1;
        *reinterpret_cast<float4*>(&xs[(4 * ti + 2) * XS_LD + 4 * tj]) = r2;
        *reinterpret_cast<float4*>(&xs[(4 * ti + 3) * XS_LD + 4 * tj]) = r3;
        // 4x4 transpose into swizzled xt
        *reinterpret_cast<float4*>(&xt[swz_word(4 * tj + 0, 4 * ti)]) =
            make_float4(r0.x, r1.x, r2.x, r3.x);
        *reinterpret_cast<float4*>(&xt[swz_word(4 * tj + 1, 4 * ti)]) =
            make_float4(r0.y, r1.y, r2.y, r3.y);
        *reinterpret_cast<float4*>(&xt[swz_word(4 * tj + 2, 4 * ti)]) =
            make_float4(r0.z, r1.z, r2.z, r3.z);
        *reinterpret_cast<float4*>(&xt[swz_word(4 * tj + 3, 4 * ti)]) =
            make_float4(r0.w, r1.w, r2.w, r3.w);
    }
    __syncthreads();

    const int kq = tid & 31;     // 4-k chunk index
    const int cg = tid >> 5;     // 0..7 ; owns c0 = C0+cg, c1 = C0+cg+8

    float au0[4] = {0,0,0,0}, au1[4] = {0,0,0,0};
    float av0[4] = {0,0,0,0}, av1[4] = {0,0,0,0};

    // ---- fused u+v loop: 2 b128 + 2 b64 -> 16 FMA per iter ----
    #pragma unroll 4
    for (int i = 0; i < KDIM; ++i) {
        const float4 xv = *reinterpret_cast<const float4*>(&xs[i * XS_LD + 4 * kq]);
        const float4 tv = *reinterpret_cast<const float4*>(&xt[swz_word(i, 4 * kq)]);
        const float2 wu = wpr[i][cg];
        const float2 wv = wpc[i][cg];
        au0[0] = fmaf(wu.x, xv.x, au0[0]); au0[1] = fmaf(wu.x, xv.y, au0[1]);
        au0[2] = fmaf(wu.x, xv.z, au0[2]); au0[3] = fmaf(wu.x, xv.w, au0[3]);
        au1[0] = fmaf(wu.y, xv.x, au1[0]); au1[1] = fmaf(wu.y, xv.y, au1[1]);
        au1[2] = fmaf(wu.y, xv.z, au1[2]); au1[3] = fmaf(wu.y, xv.w, au1[3]);
        av0[0] = fmaf(wv.x, tv.x, av0[0]); av0[1] = fmaf(wv.x, tv.y, av0[1]);
        av0[2] = fmaf(wv.x, tv.z, av0[2]); av0[3] = fmaf(wv.x, tv.w, av0[3]);
        av1[0] = fmaf(wv.y, tv.x, av1[0]); av1[1] = fmaf(wv.y, tv.y, av1[1]);
        av1[2] = fmaf(wv.y, tv.z, av1[2]); av1[3] = fmaf(wv.y, tv.w, av1[3]);
    }

    // ---- dot + bias, then reduce over the 32 kq lanes ----
    const int c0 = C0 + cg, c1 = C0 + cg + 8;
    const float br0 = b_row[c0], bc0 = b_col[c0];
    const float br1 = b_row[c1], bc1 = b_col[c1];

    float p0 = 0.f, p1 = 0.f;
    #pragma unroll
    for (int q = 0; q < 4; ++q) {
        p0 += (au0[q] + br0) * (av0[q] + bc0);
        p1 += (au1[q] + br1) * (av1[q] + bc1);
    }
    #pragma unroll
    for (int off = 16; off; off >>= 1) {
        p0 += __shfl_xor(p0, off, 32);
        p1 += __shfl_xor(p1, off, 32);
    }
    if (kq == 0) {
        s_out[b * CDIM + c0] = p0;
        s_out[b * CDIM + c1] = p1;
    }
}

// grid = 2048 (two slabs per block), block = 256. Plain float4 stores.
__global__ __launch_bounds__(256) void bcast_kernel(
    const float* __restrict__ s, float* __restrict__ out)
{
    #pragma unroll
    for (int slab = 0; slab < 2; ++slab) {
        const int bc = blockIdx.x * 2 + slab;
        const float val = s[bc];
        float4 v4;
        v4.x = v4.y = v4.z = v4.w = val;
        float4* o = reinterpret_cast<float4*>(out) + (size_t)bc * 4096;
        #pragma unroll
        for (int r = 0; r < 16; ++r) {
            o[threadIdx.x + 256 * r] = v4;
        }
    }
}

extern "C" void kernel_launch(void* const* d_in, const int* in_sizes, int n_in,
                              void* d_out, int out_size, void* d_ws, size_t ws_size,
                              hipStream_t stream) {
    const float* x     = (const float*)d_in[0];
    const float* w_col = (const float*)d_in[1];
    const float* b_col = (const float*)d_in[2];
    const float* w_row = (const float*)d_in[3];
    const float* b_row = (const float*)d_in[4];
    float* out  = (float*)d_out;
    float* s_ws = (float*)d_ws;   // 4096 floats of scratch

    compute_s_kernel<<<256, 256, 0, stream>>>(x, w_col, b_col, w_row, b_row, s_ws);
    bcast_kernel<<<2048, 256, 0, stream>>>(s_ws, out);
}